// Round 14
// baseline (705.011 us; speedup 1.0000x reference)
//
#include <hip/hip_runtime.h>

typedef float f32x2 __attribute__((ext_vector_type(2)));
typedef float f32x4 __attribute__((ext_vector_type(4)));

#define BB 256
#define TT 1024
#define HH 128
#define CC 2
#define NG 2    // independent recurrence groups per block (4 waves each)

// tanh(u) = 1 - 2/(exp(2u)+1); branchless. Validated R3-R12: absmax 9.77e-4.
__device__ __forceinline__ float ftanh(float u) {
    float e = __expf(2.0f * u);
    float r = __builtin_amdgcn_rcpf(e + 1.0f);
    return fmaf(-2.0f, r, 1.0f);
}

// broadcast lane j's value to all lanes via SGPR (VALU pipe, no LDS)
__device__ __forceinline__ float bcast(float v, int j) {
    return __int_as_float(__builtin_amdgcn_readlane(__float_as_int(v), j));
}

// v + cross-lane(v) via DPP: VALU pipe, no LDS.
#define DPP_ADD(v, ctrl)                                                     \
    ((v) + __int_as_float(__builtin_amdgcn_mov_dpp(                          \
         __float_as_int(v), (ctrl), 0xF, 0xF, true)))

__global__ __launch_bounds__(512, 1) void rnn_kernel(
    const float* __restrict__ x, const float* __restrict__ W_ih,
    const float* __restrict__ W_hh, const float* __restrict__ b_ih,
    const float* __restrict__ b_hh, const float* __restrict__ W_fc,
    const float* __restrict__ b_fc, float* __restrict__ out)
{
    const int b   = blockIdx.x;         // 0..127
    const int tid = threadIdx.x;        // 0..511
    const int g   = tid >> 8;           // recurrence group 0/1 (indep. batch rows)
    const int t2  = tid & 255;          // index within group
    const int l   = tid & 63;
    const int wv  = (tid >> 6) & 3;     // wave within group
    const int lq  = l & 31;
    const int kb  = wv << 5;            // this wave's k-quarter base
    const int rA  = l, rB = l + 64;     // partial rows this lane computes
    const int rF  = kb + lq;            // row this wave finalizes (dup lanes 32..63)

    __shared__ float xs[NG][TT + 8];    // input sequences (+pad)
    __shared__ f32x2 p2[2][NG][4][64];  // [buf][group][src wave][lane] = {pA,pB}
    __shared__ f32x2 qp[4][NG][4];      // [t&3][group][wave] logit partials

    // preload x row for this group (256 lanes x f32x4, coalesced)
    {
        const f32x4* xr = (const f32x4*)(x + (size_t)(NG * b + g) * TT);
        ((f32x4*)xs[g])[t2] = xr[t2];
    }
    if (t2 < 8) xs[g][TT + t2] = 0.f;   // prefetch pad

    const float wih  = W_ih[rF];
    const float bias = b_ih[rF] + b_hh[rF];
    // split-class: lanes 0..31 carry class 0, lanes 32..63 (dup rows) class 1
    const float wfs  = (l < 32) ? W_fc[rF] : W_fc[HH + rF];
    const float bf0  = b_fc[0], bf1 = b_fc[1];

    // per-lane weights: rows rA,rB over k in [kb, kb+32) -> 64 floats
    float wa[32], wb[32];
    {
        const f32x4* a4 = (const f32x4*)(W_hh + (size_t)rA * HH + kb);
        const f32x4* b4 = (const f32x4*)(W_hh + (size_t)rB * HH + kb);
        #pragma unroll
        for (int j = 0; j < 8; ++j) {
            f32x4 va = a4[j], vb = b4[j];
            wa[4*j+0] = va.x; wa[4*j+1] = va.y; wa[4*j+2] = va.z; wa[4*j+3] = va.w;
            wb[4*j+0] = vb.x; wb[4*j+1] = vb.y; wb[4*j+2] = vb.z; wb[4*j+3] = vb.w;
        }
    }

    float hn = 0.f, base = 0.f;         // h_t[rF]; u-base (set in H1, used in H2)
    float* o = out + (size_t)(NG * b + g) * TT * CC;

    __syncthreads();                    // xs visible
    float xcur = xs[g][0];

// H1(T): matvec(h_T) -> ship partials; DPP logits(h_T) -> qp; compute u-base.
#define H1(T) {                                                              \
        const int buf_ = (T) & 1, qb_ = (T) & 3;                             \
        float aA0 = 0.f, aA1 = 0.f, aB0 = 0.f, aB1 = 0.f;                    \
        _Pragma("unroll")                                                    \
        for (int k = 0; k < 32; k += 2) {                                    \
            float s0 = bcast(hn, k);                                         \
            float s1 = bcast(hn, k + 1);                                     \
            aA0 = fmaf(wa[k],     s0, aA0);                                  \
            aB0 = fmaf(wb[k],     s0, aB0);                                  \
            aA1 = fmaf(wa[k + 1], s1, aA1);                                  \
            aB1 = fmaf(wb[k + 1], s1, aB1);                                  \
        }                                                                    \
        f32x2 pr = { aA0 + aA1, aB0 + aB1 };                                 \
        p2[buf_][g][wv][l] = pr;                                             \
        float q = wfs * hn;                                                  \
        q = DPP_ADD(q, 0xB1);                                                \
        q = DPP_ADD(q, 0x4E);                                                \
        q = DPP_ADD(q, 0x124);                                               \
        q = DPP_ADD(q, 0x128);                                               \
        float q0 = bcast(q, 0)  + bcast(q, 16);                              \
        float q1 = bcast(q, 32) + bcast(q, 48);                              \
        if (l == 0) qp[qb_][g][wv] = f32x2{q0, q1};                          \
        base = fmaf(xcur, wih, bias);                                        \
        xcur = xs[g][(T) + 1];                                               \
    }

// H2(T): store out[T-1]=logits(h_T); combine partials; tanh -> h_{T+1}.
#define H2(T) {                                                              \
        const int buf_ = (T) & 1, qb_ = (T) & 3;                             \
        if ((T) > 0 && t2 == 0) {                                            \
            f32x2 s = (qp[qb_][g][0] + qp[qb_][g][1])                        \
                    + (qp[qb_][g][2] + qp[qb_][g][3]);                       \
            s.x += bf0; s.y += bf1;                                          \
            *(f32x2*)(o + ((T) - 1) * CC) = s;                               \
        }                                                                    \
        const float* pf = (const float*)&p2[buf_][g][0][0]                   \
                        + ((((wv & 1) << 5) + lq) << 1) + (wv >> 1);         \
        float p0 = pf[0], p1 = pf[128], pv2 = pf[256], pv3 = pf[384];        \
        hn = ftanh(base + ((p0 + p1) + (pv2 + pv3)));                        \
    }

    // Phase-shifted: in every barrier interval, one group runs issue-heavy H1
    // while the other runs latency-heavy H2 -> complementary SIMD overlap.
    // Write->read separation: each group's p2/qp write and read are separated
    // by >=1 block barrier in both phase slots.
    #pragma unroll 2
    for (int t = 0; t < TT; ++t) {
        if (g == 0) { H1(t) } else if (t > 0) { H2(t - 1) }
        __syncthreads();                // A
        if (g == 0) { H2(t) } else { H1(t) }
        __syncthreads();                // B
    }

    // epilogue: group 1 still owes H2(TT-1) (produces h_TT, stores out[TT-2])
    if (g == 1) { H2(TT - 1) }

    // final logits(h_TT) for both groups
    {
        float q = wfs * hn;
        q = DPP_ADD(q, 0xB1);
        q = DPP_ADD(q, 0x4E);
        q = DPP_ADD(q, 0x124);
        q = DPP_ADD(q, 0x128);
        float q0 = bcast(q, 0)  + bcast(q, 16);
        float q1 = bcast(q, 32) + bcast(q, 48);
        if (l == 0) qp[0][g][wv] = f32x2{q0, q1};
    }
    __syncthreads();
    if (t2 == 0) {
        f32x2 s = (qp[0][g][0] + qp[0][g][1]) + (qp[0][g][2] + qp[0][g][3]);
        s.x += bf0; s.y += bf1;
        *(f32x2*)(o + (TT - 1) * CC) = s;
    }
#undef H1
#undef H2
}

extern "C" void kernel_launch(void* const* d_in, const int* in_sizes, int n_in,
                              void* d_out, int out_size, void* d_ws, size_t ws_size,
                              hipStream_t stream) {
    const float* x    = (const float*)d_in[0];
    const float* W_ih = (const float*)d_in[1];
    const float* W_hh = (const float*)d_in[2];
    const float* b_ih = (const float*)d_in[3];
    const float* b_hh = (const float*)d_in[4];
    const float* W_fc = (const float*)d_in[5];
    const float* b_fc = (const float*)d_in[6];
    float* out = (float*)d_out;

    rnn_kernel<<<BB / NG, 512, 0, stream>>>(x, W_ih, W_hh, b_ih, b_hh, W_fc, b_fc, out);
}

// Round 15
// 515.594 us; speedup vs baseline: 1.3674x; 1.3674x over previous
//
#include <hip/hip_runtime.h>

typedef float f32x2 __attribute__((ext_vector_type(2)));
typedef float f32x4 __attribute__((ext_vector_type(4)));

#define BB 256
#define TT 1024
#define HH 128
#define CC 2

// tanh(u) = 1 - 2/(exp(2u)+1); branchless. Validated R3-R13: absmax 9.77e-4.
__device__ __forceinline__ float ftanh(float u) {
    float e = __expf(2.0f * u);
    float r = __builtin_amdgcn_rcpf(e + 1.0f);
    return fmaf(-2.0f, r, 1.0f);
}

// broadcast lane j's value to all lanes via SGPR (VALU pipe, no LDS)
__device__ __forceinline__ float bcast(float v, int j) {
    return __int_as_float(__builtin_amdgcn_readlane(__float_as_int(v), j));
}

// v + cross-lane(v) via DPP: VALU pipe, no LDS.
#define DPP_ADD(v, ctrl)                                                     \
    ((v) + __int_as_float(__builtin_amdgcn_mov_dpp(                          \
         __float_as_int(v), (ctrl), 0xF, 0xF, true)))

// AGPR stash: values of asm class "a" live in AGPRs and can NEVER be
// rematerialized by the allocator (asm is opaque) -> weights stay resident,
// killing the per-step 16x buffer_load_dwordx4 L1 reload (R10's hidden stall).
#define AGPR_WRITE(dst, src) \
    asm("v_accvgpr_write_b32 %0, %1" : "=a"(dst) : "v"(src))
#define AGPR_READ(dst, src) \
    asm("v_accvgpr_read_b32 %0, %1" : "=v"(dst) : "a"(src))

__global__ __launch_bounds__(256, 1) void rnn_kernel(
    const float* __restrict__ x, const float* __restrict__ W_ih,
    const float* __restrict__ W_hh, const float* __restrict__ b_ih,
    const float* __restrict__ b_hh, const float* __restrict__ W_fc,
    const float* __restrict__ b_fc, float* __restrict__ out)
{
    const int b   = blockIdx.x;         // 0..255
    const int tid = threadIdx.x;        // 0..255
    const int l   = tid & 63;
    const int wv  = tid >> 6;           // 0..3
    const int lq  = l & 31;
    const int kb  = wv << 5;            // this wave's k-quarter base
    const int rA  = l, rB = l + 64;     // partial rows this lane computes
    const int rF  = kb + lq;            // row this wave finalizes (dup lanes 32..63)

    __shared__ float xs[TT + 8];        // input sequence (+pad for prefetch)
    __shared__ f32x2 p2[2][4][64];      // [buf][src wave][lane] = {pA, pB}
    __shared__ f32x2 qp[4][4];          // [t&3][wave] logit partials

    // preload x row (256 lanes x f32x4, coalesced)
    {
        const f32x4* xr = (const f32x4*)(x + (size_t)b * TT);
        ((f32x4*)xs)[tid] = xr[tid];
    }
    if (tid < 8) xs[TT + tid] = 0.f;    // prefetch pad

    const float wih  = W_ih[rF];
    const float bias = b_ih[rF] + b_hh[rF];
    // split-class: lanes 0..31 carry class 0, lanes 32..63 (dup rows) class 1
    const float wfs  = (l < 32) ? W_fc[rF] : W_fc[HH + rF];
    const float bf0  = b_fc[0], bf1 = b_fc[1];

    // per-lane weights: rows rA,rB over k in [kb, kb+32) -> 64 floats,
    // loaded once and parked in 64 AGPRs (cannot be rematerialized).
    float wa_a[32], wb_a[32];           // asm class "a" values (AGPRs)
    {
        const f32x4* a4 = (const f32x4*)(W_hh + (size_t)rA * HH + kb);
        const f32x4* b4 = (const f32x4*)(W_hh + (size_t)rB * HH + kb);
        #pragma unroll
        for (int j = 0; j < 8; ++j) {
            f32x4 va = a4[j], vb = b4[j];
            AGPR_WRITE(wa_a[4*j+0], va.x); AGPR_WRITE(wa_a[4*j+1], va.y);
            AGPR_WRITE(wa_a[4*j+2], va.z); AGPR_WRITE(wa_a[4*j+3], va.w);
            AGPR_WRITE(wb_a[4*j+0], vb.x); AGPR_WRITE(wb_a[4*j+1], vb.y);
            AGPR_WRITE(wb_a[4*j+2], vb.z); AGPR_WRITE(wb_a[4*j+3], vb.w);
        }
    }

    float hn = 0.f;                     // h_t[rF] (lanes 32..63 duplicate 0..31)
    float* o = out + (size_t)b * TT * CC;

    __syncthreads();                    // xs visible
    float xcur = xs[0];

    #pragma unroll 4
    for (int t = 0; t < TT; ++t) {
        const int buf = t & 1, qb = t & 3;

        // ---- partial matvec over this wave's k-quarter.
        // h via readlane (lane k holds h[kb+k]); weights via accvgpr_read
        // (2-cyc VALU, zero memory-pipe traffic).
        float aA0 = 0.f, aA1 = 0.f, aB0 = 0.f, aB1 = 0.f;
        #pragma unroll
        for (int k = 0; k < 32; k += 2) {
            float w0a, w0b, w1a, w1b;
            AGPR_READ(w0a, wa_a[k]);     AGPR_READ(w0b, wb_a[k]);
            AGPR_READ(w1a, wa_a[k + 1]); AGPR_READ(w1b, wb_a[k + 1]);
            float s0 = bcast(hn, k);
            float s1 = bcast(hn, k + 1);
            aA0 = fmaf(w0a, s0, aA0);
            aB0 = fmaf(w0b, s0, aB0);
            aA1 = fmaf(w1a, s1, aA1);
            aB1 = fmaf(w1b, s1, aB1);
        }
        f32x2 pr = { aA0 + aA1, aB0 + aB1 };
        p2[buf][wv][l] = pr;            // b64 ship, 2-way alias = free

        // ---- logit partials of h_t: split-class DPP reduce (R12-proven)
        {
            float q = wfs * hn;
            q = DPP_ADD(q, 0xB1);       // + xor1 (quad)
            q = DPP_ADD(q, 0x4E);       // + xor2 (quad)
            q = DPP_ADD(q, 0x124);      // + ror4 (row16)
            q = DPP_ADD(q, 0x128);      // + ror8 (row16) -> lane = row16 sum
            float q0 = bcast(q, 0)  + bcast(q, 16);   // class 0 (lanes 0..31)
            float q1 = bcast(q, 32) + bcast(q, 48);   // class 1 (lanes 32..63)
            if (l == 0) qp[qb][wv] = f32x2{q0, q1};
        }

        // pre-barrier: u-base and x prefetch (off the post-barrier chain)
        const float base  = fmaf(xcur, wih, bias);
        const float xnext = xs[t + 1];

        __syncthreads();                // the single per-step barrier

        // ---- out[t-1] = logits(h_t): qp[t&3] written THIS iteration pre-barrier
        if (t > 0 && tid == 0) {
            f32x2 s = (qp[qb][0] + qp[qb][1]) + (qp[qb][2] + qp[qb][3]);
            s.x += bf0; s.y += bf1;
            *(f32x2*)(o + (t - 1) * CC) = s;
        }

        // ---- combine the 4 k-quarter partials of row rF (R10-proven pattern)
        const float* pf = (const float*)&p2[buf][0][0]
                        + ((((wv & 1) << 5) + lq) << 1) + (wv >> 1);
        float p0 = pf[0], p1 = pf[128], pv2 = pf[256], pv3 = pf[384];
        hn = ftanh(base + ((p0 + p1) + (pv2 + pv3)));
        xcur = xnext;
    }

    // epilogue: out[TT-1] = logits(h_TT)
    {
        float q = wfs * hn;
        q = DPP_ADD(q, 0xB1);
        q = DPP_ADD(q, 0x4E);
        q = DPP_ADD(q, 0x124);
        q = DPP_ADD(q, 0x128);
        float q0 = bcast(q, 0)  + bcast(q, 16);
        float q1 = bcast(q, 32) + bcast(q, 48);
        if (l == 0) qp[0][wv] = f32x2{q0, q1};
    }
    __syncthreads();
    if (tid == 0) {
        f32x2 s = (qp[0][0] + qp[0][1]) + (qp[0][2] + qp[0][3]);
        s.x += bf0; s.y += bf1;
        *(f32x2*)(o + (TT - 1) * CC) = s;
    }
}

extern "C" void kernel_launch(void* const* d_in, const int* in_sizes, int n_in,
                              void* d_out, int out_size, void* d_ws, size_t ws_size,
                              hipStream_t stream) {
    const float* x    = (const float*)d_in[0];
    const float* W_ih = (const float*)d_in[1];
    const float* W_hh = (const float*)d_in[2];
    const float* b_ih = (const float*)d_in[3];
    const float* b_hh = (const float*)d_in[4];
    const float* W_fc = (const float*)d_in[5];
    const float* b_fc = (const float*)d_in[6];
    float* out = (float*)d_out;

    rnn_kernel<<<BB, 256, 0, stream>>>(x, W_ih, W_hh, b_ih, b_hh, W_fc, b_fc, out);
}

// Round 16
// 442.241 us; speedup vs baseline: 1.5942x; 1.1659x over previous
//
#include <hip/hip_runtime.h>

typedef float f32x2 __attribute__((ext_vector_type(2)));
typedef float f32x4 __attribute__((ext_vector_type(4)));

#define BB 256
#define TT 1024
#define HH 128
#define CC 2

// tanh(u) = 1 - 2/(exp(2u)+1); branchless. Validated R3-R14: absmax 9.77e-4.
__device__ __forceinline__ float ftanh(float u) {
    float e = __expf(2.0f * u);
    float r = __builtin_amdgcn_rcpf(e + 1.0f);
    return fmaf(-2.0f, r, 1.0f);
}

// broadcast lane j's value to all lanes via SGPR (VALU pipe, no LDS)
__device__ __forceinline__ float bcast(float v, int j) {
    return __int_as_float(__builtin_amdgcn_readlane(__float_as_int(v), j));
}

// v + cross-lane(v) via DPP: VALU pipe, no LDS.
#define DPP_ADD(v, ctrl)                                                     \
    ((v) + __int_as_float(__builtin_amdgcn_mov_dpp(                          \
         __float_as_int(v), (ctrl), 0xF, 0xF, true)))

__global__ __launch_bounds__(256, 1) void rnn_kernel(
    const float* __restrict__ x, const float* __restrict__ W_ih,
    const float* __restrict__ W_hh, const float* __restrict__ b_ih,
    const float* __restrict__ b_hh, const float* __restrict__ W_fc,
    const float* __restrict__ b_fc, float* __restrict__ out)
{
    const int b   = blockIdx.x;         // 0..255
    const int tid = threadIdx.x;        // 0..255
    const int l   = tid & 63;
    const int wv  = tid >> 6;           // 0..3
    const int lq  = l & 31;
    const int kb  = wv << 5;            // this wave's k-quarter base
    const int rA  = l, rB = l + 64;     // partial rows this lane computes
    const int rF  = kb + lq;            // row this wave finalizes (dup lanes 32..63)

    __shared__ float xs[TT + 8];        // input sequence (+pad for prefetch)
    __shared__ f32x2 p2[2][4][64];      // [buf][src wave][lane] = {pA, pB}
    __shared__ f32x2 qp[4][4];          // [t&3][wave] logit partials
    __shared__ f32x2 obuf[16];          // batched output ring (wave 0 only)

    // preload x row (256 lanes x f32x4, coalesced)
    {
        const f32x4* xr = (const f32x4*)(x + (size_t)b * TT);
        ((f32x4*)xs)[tid] = xr[tid];
    }
    if (tid < 8) xs[TT + tid] = 0.f;    // prefetch pad

    const float wih  = W_ih[rF];
    const float bias = b_ih[rF] + b_hh[rF];
    // split-class: lanes 0..31 carry class 0, lanes 32..63 (dup rows) class 1
    const float wfs  = (l < 32) ? W_fc[rF] : W_fc[HH + rF];
    const float bf0  = b_fc[0], bf1 = b_fc[1];

    // per-lane weights: rows rA,rB over k in [kb, kb+32) -> 64 floats.
    // Compiler re-fetches from L1 per step; R14 proved this is cheaper than
    // AGPR parking (VALU can't source AGPRs; accvgpr_read costs more issue).
    float wa[32], wb[32];
    {
        const f32x4* a4 = (const f32x4*)(W_hh + (size_t)rA * HH + kb);
        const f32x4* b4 = (const f32x4*)(W_hh + (size_t)rB * HH + kb);
        #pragma unroll
        for (int j = 0; j < 8; ++j) {
            f32x4 va = a4[j], vb = b4[j];
            wa[4*j+0] = va.x; wa[4*j+1] = va.y; wa[4*j+2] = va.z; wa[4*j+3] = va.w;
            wb[4*j+0] = vb.x; wb[4*j+1] = vb.y; wb[4*j+2] = vb.z; wb[4*j+3] = vb.w;
        }
        #pragma unroll
        for (int k = 0; k < 32; ++k)
            asm volatile("" : "+v"(wa[k]), "+v"(wb[k]));
    }

    float hn = 0.f;                     // h_t[rF] (lanes 32..63 duplicate 0..31)
    float* o = out + (size_t)b * TT * CC;

    __syncthreads();                    // xs visible
    float xcur = xs[0];

    #pragma unroll 4
    for (int t = 0; t < TT; ++t) {
        const int buf = t & 1, qb = t & 3;

        // ---- pre-barrier: partial matvec over this wave's k-quarter only.
        // lane k (k<32) holds h[kb+k] in hn -> bcast(hn,k) = h[kb+k].
        float aA0 = 0.f, aA1 = 0.f, aB0 = 0.f, aB1 = 0.f;
        #pragma unroll
        for (int k = 0; k < 32; k += 2) {
            float s0 = bcast(hn, k);
            float s1 = bcast(hn, k + 1);
            aA0 = fmaf(wa[k],     s0, aA0);
            aB0 = fmaf(wb[k],     s0, aB0);
            aA1 = fmaf(wa[k + 1], s1, aA1);
            aB1 = fmaf(wb[k + 1], s1, aB1);
        }
        p2[buf][wv][l] = f32x2{ aA0 + aA1, aB0 + aB1 };  // b64 ship
        const float xnext = xs[t + 1];  // prefetch (fire-and-forget)

        __syncthreads();                // the single per-step barrier

        // ---- post-barrier: issue combine reads, then fill their ~120-cyc
        // latency shadow with the logit tree + output bookkeeping.
        const float* pf = (const float*)&p2[buf][0][0]
                        + ((((wv & 1) << 5) + lq) << 1) + (wv >> 1);
        float p0 = pf[0], p1 = pf[128], pv2 = pf[256], pv3 = pf[384];

        {   // logits of h_t (hn still = h_t): split-class DPP reduce
            float q = wfs * hn;
            q = DPP_ADD(q, 0xB1);       // + xor1 (quad)
            q = DPP_ADD(q, 0x4E);       // + xor2 (quad)
            q = DPP_ADD(q, 0x124);      // + ror4 (row16)
            q = DPP_ADD(q, 0x128);      // + ror8 (row16) -> lane = row16 sum
            float q0 = bcast(q, 0)  + bcast(q, 16);   // class 0
            float q1 = bcast(q, 32) + bcast(q, 48);   // class 1
            if (l == 0) qp[qb][wv] = f32x2{q0, q1};
        }
        // out[t-2] entry: qp[(t-1)&3] = logits(h_{t-1}), written at step t-1
        // post-barrier, made visible by this step's barrier.
        if (t >= 2 && tid == 0) {
            const int pq = (t - 1) & 3;
            f32x2 s = (qp[pq][0] + qp[pq][1]) + (qp[pq][2] + qp[pq][3]);
            s.x += bf0; s.y += bf1;
            obuf[(t - 2) & 15] = s;     // same-wave LDS: ordered vs flush below
        }
        // flush a full 16-entry window every 16 steps (coalesced 128B store;
        // amortizes the global-store vmcnt cost over 16 barriers)
        if ((t & 15) == 1 && t >= 17 && tid < 32) {
            ((float*)(o + (t - 17) * CC))[tid] = ((const float*)obuf)[tid];
        }

        const float base = fmaf(xcur, wih, bias);
        xcur = xnext;
        // combine arrives here, shadow filled:
        hn = ftanh(base + ((p0 + p1) + (pv2 + pv3)));
    }

    // ---- epilogue ----
    // logits(h_TT) -> qp[TT&3] = qp[0]
    {
        float q = wfs * hn;
        q = DPP_ADD(q, 0xB1);
        q = DPP_ADD(q, 0x4E);
        q = DPP_ADD(q, 0x124);
        q = DPP_ADD(q, 0x128);
        float q0 = bcast(q, 0)  + bcast(q, 16);
        float q1 = bcast(q, 32) + bcast(q, 48);
        if (l == 0) qp[0][wv] = f32x2{q0, q1};
    }
    __syncthreads();
    if (tid == 0) {
        // out[TT-2] = logits(h_{TT-1}) from qp[(TT-1)&3] = qp[3]
        f32x2 s = (qp[3][0] + qp[3][1]) + (qp[3][2] + qp[3][3]);
        s.x += bf0; s.y += bf1;
        *(f32x2*)(o + (TT - 2) * CC) = s;
        // out[TT-1] = logits(h_TT) from qp[0]
        f32x2 s2 = (qp[0][0] + qp[0][1]) + (qp[0][2] + qp[0][3]);
        s2.x += bf0; s2.y += bf1;
        *(f32x2*)(o + (TT - 1) * CC) = s2;
    }
    // residual ring: out[1008..1021] live in obuf slots 0..13 (28 floats)
    if (tid < 28) {
        ((float*)(o + 1008 * CC))[tid] = ((const float*)obuf)[tid];
    }
}

extern "C" void kernel_launch(void* const* d_in, const int* in_sizes, int n_in,
                              void* d_out, int out_size, void* d_ws, size_t ws_size,
                              hipStream_t stream) {
    const float* x    = (const float*)d_in[0];
    const float* W_ih = (const float*)d_in[1];
    const float* W_hh = (const float*)d_in[2];
    const float* b_ih = (const float*)d_in[3];
    const float* b_hh = (const float*)d_in[4];
    const float* W_fc = (const float*)d_in[5];
    const float* b_fc = (const float*)d_in[6];
    float* out = (float*)d_out;

    rnn_kernel<<<BB, 256, 0, stream>>>(x, W_ih, W_hh, b_ih, b_hh, W_fc, b_fc, out);
}